// Round 13
// baseline (667.921 us; speedup 1.0000x reference)
//
#include <hip/hip_runtime.h>
#include <math.h>

#define ROUTIT 6
#define CAP 12   // cached edges per wave: 2 waves * 12 * 64 * 8B = 12 KB/block -> 13 blocks/CU
#define WPB 2    // waves per block in route_kernel
#define SCB 256  // scan blocks

__device__ __forceinline__ int load_idx(const void* p, long long i, int is64)
{
    if (is64) return (int)((const long long*)p)[i];
    return ((const int*)p)[i];
}

// ---------------------------------------------------------------------------
// Cross-lane reductions on the VALU pipe only (DPP + readlane) — verified r8-12.
// ---------------------------------------------------------------------------
template <int CTRL>
__device__ __forceinline__ float dpp_add(float x)
{
    int y = __builtin_amdgcn_update_dpp(0, __float_as_int(x), CTRL, 0xf, 0xf, true);
    return x + __int_as_float(y);
}

__device__ __forceinline__ float rowsum16(float p)
{
    p = dpp_add<0xB1>(p);   // quad_perm xor1
    p = dpp_add<0x4E>(p);   // quad_perm xor2
    p = dpp_add<0x124>(p);  // row_ror:4
    p = dpp_add<0x128>(p);  // row_ror:8
    return p;
}

__device__ __forceinline__ float xrow_total(float ex)
{
    float t = dpp_add<0x142>(ex);  // row_bcast15
    t = dpp_add<0x143>(t);         // row_bcast31 -> lanes 48..63 hold total
    return __uint_as_float((unsigned)__builtin_amdgcn_readlane(__float_as_uint(t), 63));
}

__device__ __forceinline__ void edge_acc(float zx, float zy, float cx, float cy,
                                         float& a0, float& a1)
{
    float p = zx * cx + zy * cy;
    p = rowsum16(p);                    // 32-elem channel dot, |p| <= 1
    float ex = __expf(p);
    float d  = xrow_total(ex);          // softmax denom over 4 channels
    float w  = ex * __builtin_amdgcn_rcpf(d);
    a0 += w * zx;
    a1 += w * zy;
}

// ---------------------------------------------------------------------------
// GEMM + per-channel L2 normalize (fp32 h) — v3.
// Round-8 version was DS-pipe-bound: per lc it did 4 scalar ds_read_b32 (xs)
// + 1 strided ds_read_b128 (WT). v3 drops the xs tile: each x float4 is read
// ONCE from global by a 32-lane broadcast group (L2-hot; total x traffic is
// exactly 51 MB — unlike round-10's v2 which re-fetched 32x inside the quad
// loop). Only WT stays in LDS. DS ops/wave drop ~5x -> FMA-bound.
// ---------------------------------------------------------------------------
__global__ __launch_bounds__(256)
void gemm_norm_kernel(const float* __restrict__ x, const float* __restrict__ W,
                      const float* __restrict__ b, float* __restrict__ h, int n)
{
    __shared__ float WT[32 * 132];    // WT[lc*132 + j] = W[j][l0+lc]

    const int tid  = threadIdx.x;
    const int jc   = tid & 31;        // col group: cols jc*4 .. jc*4+3
    const int rg   = tid >> 5;        // row group: rows rg*4 .. rg*4+3
    const int row0 = blockIdx.x * 32;

    float4 bb = ((const float4*)b)[jc];
    float acc[4][4];
    #pragma unroll
    for (int ri = 0; ri < 4; ++ri) {
        acc[ri][0] = bb.x; acc[ri][1] = bb.y; acc[ri][2] = bb.z; acc[ri][3] = bb.w;
    }

    for (int l0 = 0; l0 < 128; l0 += 32) {
        __syncthreads();
        for (int t = 0; t < 16; ++t) {
            int idx = t * 256 + tid;
            int j = idx >> 5, lc = idx & 31;
            WT[lc * 132 + j] = W[j * 128 + l0 + lc];
        }
        __syncthreads();

        #pragma unroll 2
        for (int q = 0; q < 8; ++q) {           // lc quads
            float4 xq[4];
            #pragma unroll
            for (int ri = 0; ri < 4; ++ri) {
                int row = row0 + rg * 4 + ri;
                row = row < n ? row : n - 1;    // safety clamp
                xq[ri] = *(const float4*)(x + (size_t)row * 128 + l0 + q * 4);
            }
            #pragma unroll
            for (int k = 0; k < 4; ++k) {
                float4 wt = ((const float4*)(WT + (q * 4 + k) * 132))[jc];
                #pragma unroll
                for (int ri = 0; ri < 4; ++ri) {
                    float xv = (k == 0) ? xq[ri].x : (k == 1) ? xq[ri].y
                             : (k == 2) ? xq[ri].z : xq[ri].w;
                    acc[ri][0] += xv * wt.x;
                    acc[ri][1] += xv * wt.y;
                    acc[ri][2] += xv * wt.z;
                    acc[ri][3] += xv * wt.w;
                }
            }
        }
    }

    #pragma unroll
    for (int ri = 0; ri < 4; ++ri) {
        float ss = acc[ri][0]*acc[ri][0] + acc[ri][1]*acc[ri][1]
                 + acc[ri][2]*acc[ri][2] + acc[ri][3]*acc[ri][3];
        ss += __shfl_xor(ss, 1);
        ss += __shfl_xor(ss, 2);
        ss += __shfl_xor(ss, 4);
        float inv = 1.0f / fmaxf(sqrtf(ss), 1e-12f);
        int row = row0 + rg * 4 + ri;
        if (row < n) {
            float4 o;
            o.x = acc[ri][0]*inv; o.y = acc[ri][1]*inv;
            o.z = acc[ri][2]*inv; o.w = acc[ri][3]*inv;
            ((float4*)(h + (size_t)row * 128))[jc] = o;
        }
    }
}

// ---------------------------------------------------------------------------
// CSR build
// ---------------------------------------------------------------------------
__global__ void zero_detect_kernel(int* __restrict__ p, int n,
                                   const int* __restrict__ raw, int* __restrict__ flag)
{
    int i = blockIdx.x * blockDim.x + threadIdx.x;
    if (i < n) p[i] = 0;
    if (i == 0) {
        int all_zero = 1;
        for (int k = 1; k < 64; k += 2)
            if (raw[k] != 0) { all_zero = 0; break; }
        *flag = all_zero;   // 1 => int64 encoding, 0 => int32
    }
}

__global__ void hist_kernel(const void* __restrict__ st, long long m, int n,
                            const int* __restrict__ idx64, int* __restrict__ cnt)
{
    long long e = (long long)blockIdx.x * blockDim.x + threadIdx.x;
    if (e < m) {
        int t = load_idx(st, m + e, *idx64);
        if (t >= 0 && t < n) atomicAdd(&cnt[t], 1);
    }
}

// ---- 3-phase parallel scan (verified round 12) ----
__global__ __launch_bounds__(256)
void scan_partial_kernel(const int* __restrict__ cnt, int n, int chunk,
                         int* __restrict__ bsum)
{
    int b = blockIdx.x, t = threadIdx.x;
    int lo = b * chunk, hi = min(lo + chunk, n);
    int s = 0;
    for (int i = lo + t; i < hi; i += 256) s += cnt[i];
    __shared__ int red[256];
    red[t] = s; __syncthreads();
    for (int off = 128; off > 0; off >>= 1) {
        if (t < off) red[t] += red[t + off];
        __syncthreads();
    }
    if (t == 0) bsum[b] = red[0];
}

__global__ __launch_bounds__(256)
void scan_offsets_kernel(const int* __restrict__ bsum, int nb,
                         int* __restrict__ boff, int* __restrict__ total)
{
    __shared__ int lds[256];
    int t = threadIdx.x;
    int v = (t < nb) ? bsum[t] : 0;
    lds[t] = v; __syncthreads();
    for (int off = 1; off < 256; off <<= 1) {
        int u = (t >= off) ? lds[t - off] : 0;
        __syncthreads();
        lds[t] += u;
        __syncthreads();
    }
    if (t < nb) boff[t] = lds[t] - v;      // exclusive
    if (t == 255) *total = lds[255];
}

__global__ __launch_bounds__(256)
void scan_write_kernel(const int* __restrict__ cnt, int n, int chunk,
                       const int* __restrict__ boff, const int* __restrict__ total,
                       int* __restrict__ row_ptr, int* __restrict__ cursor)
{
    int b = blockIdx.x, t = threadIdx.x;
    int lo = b * chunk, hi = min(lo + chunk, n);
    __shared__ int lds[256];
    int run = boff[b];
    for (int base = lo; base < hi; base += 256) {
        int i = base + t;
        int v = (i < hi) ? cnt[i] : 0;
        lds[t] = v; __syncthreads();
        for (int off = 1; off < 256; off <<= 1) {
            int u = (t >= off) ? lds[t - off] : 0;
            __syncthreads();
            lds[t] += u;
            __syncthreads();
        }
        if (i < hi) {
            int excl = run + lds[t] - v;
            row_ptr[i] = excl;
            cursor[i]  = excl;
        }
        run += lds[255];
        __syncthreads();
    }
    if (b == 0 && t == 0) row_ptr[n] = *total;
}

__global__ void scatter_kernel(const void* __restrict__ st, long long m, int n,
                               const int* __restrict__ idx64,
                               int* __restrict__ cursor, int* __restrict__ edge_src)
{
    long long e = (long long)blockIdx.x * blockDim.x + threadIdx.x;
    if (e < m) {
        int is64 = *idx64;
        int t = load_idx(st, m + e, is64);
        int s = load_idx(st, e, is64);
        if (t >= 0 && t < n) {
            int pos = atomicAdd(&cursor[t], 1);
            edge_src[pos] = s;
        }
    }
}

// ---------------------------------------------------------------------------
// Routing (round-11 structure; CAP 16->12 so 12 KB LDS/block -> 13 blocks/CU
// -> 81% wave occupancy; cache covers ~72% of replay visits).
// ---------------------------------------------------------------------------
__global__ __launch_bounds__(64 * WPB)
void route_kernel(const float* __restrict__ h, const int* __restrict__ row_ptr,
                  const int* __restrict__ edge_src, float* __restrict__ out, int n)
{
    __shared__ float2 zls[WPB][CAP][64];

    int wv   = threadIdx.x >> 6;
    int wid  = __builtin_amdgcn_readfirstlane(blockIdx.x * WPB + wv);
    int lane = threadIdx.x & 63;
    if (wid >= n) return;

    const float2* __restrict__ h2 = (const float2*)h;
    float2 c0 = h2[(size_t)wid * 64 + lane];
    float cx = c0.x, cy = c0.y;

    const int e0  = row_ptr[wid], e1 = row_ptr[wid + 1];
    const int deg = e1 - e0;
    const int nc  = deg < CAP ? deg : CAP;

    // ---- iteration 0: gather, cache in LDS, compute ----
    float a0 = cx, a1 = cy;
    {
        int j = 0;
        for (; j + 1 < nc; j += 2) {
            int sa = edge_src[e0 + j];
            int sb = edge_src[e0 + j + 1];
            float2 za = h2[(size_t)sa * 64 + lane];
            float2 zb = h2[(size_t)sb * 64 + lane];
            zls[wv][j][lane] = za;
            zls[wv][j + 1][lane] = zb;
            edge_acc(za.x, za.y, cx, cy, a0, a1);
            edge_acc(zb.x, zb.y, cx, cy, a0, a1);
        }
        if (j < nc) {
            int s = edge_src[e0 + j];
            float2 z = h2[(size_t)s * 64 + lane];
            zls[wv][j][lane] = z;
            edge_acc(z.x, z.y, cx, cy, a0, a1);
        }
        for (int e = e0 + nc; e < e1; ++e) {
            int s = edge_src[e];
            float2 z = h2[(size_t)s * 64 + lane];
            edge_acc(z.x, z.y, cx, cy, a0, a1);
        }
        float ss = rowsum16(a0 * a0 + a1 * a1);
        float inv = __builtin_amdgcn_rcpf(fmaxf(sqrtf(ss), 1e-12f));
        cx = a0 * inv; cy = a1 * inv;
    }

    // ---- iterations 1..5: replay from LDS (+ uncached tail), 4-wide ILP ----
    #pragma unroll 1
    for (int it = 1; it < ROUTIT; ++it) {
        a0 = cx; a1 = cy;
        int j = 0;
        for (; j + 3 < nc; j += 4) {
            float2 z0 = zls[wv][j][lane];
            float2 z1 = zls[wv][j + 1][lane];
            float2 z2 = zls[wv][j + 2][lane];
            float2 z3 = zls[wv][j + 3][lane];
            edge_acc(z0.x, z0.y, cx, cy, a0, a1);
            edge_acc(z1.x, z1.y, cx, cy, a0, a1);
            edge_acc(z2.x, z2.y, cx, cy, a0, a1);
            edge_acc(z3.x, z3.y, cx, cy, a0, a1);
        }
        for (; j < nc; ++j) {
            float2 z = zls[wv][j][lane];
            edge_acc(z.x, z.y, cx, cy, a0, a1);
        }
        for (int e = e0 + nc; e < e1; ++e) {
            int s = edge_src[e];
            float2 z = h2[(size_t)s * 64 + lane];
            edge_acc(z.x, z.y, cx, cy, a0, a1);
        }
        float ss = rowsum16(a0 * a0 + a1 * a1);
        float inv = __builtin_amdgcn_rcpf(fmaxf(sqrtf(ss), 1e-12f));
        cx = a0 * inv; cy = a1 * inv;
    }

    float2 o; o.x = cx; o.y = cy;
    ((float2*)out)[(size_t)wid * 64 + lane] = o;
}

// ---------------------------------------------------------------------------
extern "C" void kernel_launch(void* const* d_in, const int* in_sizes, int n_in,
                              void* d_out, int out_size, void* d_ws, size_t ws_size,
                              hipStream_t stream)
{
    const float* x       = (const float*)d_in[0];
    const void*  src_trg = d_in[1];
    const float* W       = (const float*)d_in[2];
    const float* b       = (const float*)d_in[3];
    float*       out     = (float*)d_out;

    int n = in_sizes[0] / 128;
    long long m = in_sizes[1] / 2;
    int chunk = (n + SCB - 1) / SCB;

    // workspace layout (~59 MB)
    float* h        = (float*)d_ws;                    // n*128 floats (51.2 MB)
    int*   cnt      = (int*)(h + (size_t)n * 128);     // n
    int*   row_ptr  = cnt + n;                         // n+1
    int*   cursor   = row_ptr + (n + 1);               // n
    int*   edge_src = cursor + n;                      // m ints (6.4 MB)
    int*   idx64    = edge_src + m;                    // 1 flag
    int*   bsum     = idx64 + 1;                       // SCB
    int*   boff     = bsum + SCB;                      // SCB
    int*   total    = boff + SCB;                      // 1

    hipLaunchKernelGGL(gemm_norm_kernel, dim3((n + 31) / 32), dim3(256), 0, stream,
                       x, W, b, h, n);
    hipLaunchKernelGGL(zero_detect_kernel, dim3((n + 255) / 256), dim3(256), 0, stream,
                       cnt, n, (const int*)src_trg, idx64);
    hipLaunchKernelGGL(hist_kernel, dim3((int)((m + 255) / 256)), dim3(256), 0, stream,
                       src_trg, m, n, idx64, cnt);
    hipLaunchKernelGGL(scan_partial_kernel, dim3(SCB), dim3(256), 0, stream,
                       cnt, n, chunk, bsum);
    hipLaunchKernelGGL(scan_offsets_kernel, dim3(1), dim3(256), 0, stream,
                       bsum, SCB, boff, total);
    hipLaunchKernelGGL(scan_write_kernel, dim3(SCB), dim3(256), 0, stream,
                       cnt, n, chunk, boff, total, row_ptr, cursor);
    hipLaunchKernelGGL(scatter_kernel, dim3((int)((m + 255) / 256)), dim3(256), 0, stream,
                       src_trg, m, n, idx64, cursor, edge_src);
    hipLaunchKernelGGL(route_kernel, dim3((n + WPB - 1) / WPB), dim3(64 * WPB), 0, stream,
                       h, row_ptr, edge_src, out, n);
}

// Round 14
// 609.807 us; speedup vs baseline: 1.0953x; 1.0953x over previous
//
#include <hip/hip_runtime.h>
#include <math.h>

#define ROUTIT 6
#define CAP 8    // cached edge-PAIRS per wave: 2 waves * 8 * 64 * 16B = 16 KB/block
#define WPB 2    // waves per block in route_kernel
#define SCB 256  // scan blocks

__device__ __forceinline__ int load_idx(const void* p, long long i, int is64)
{
    if (is64) return (int)((const long long*)p)[i];
    return ((const int*)p)[i];
}

// ---------------------------------------------------------------------------
// DPP helpers (VALU pipe). dpp_add verified r8-13.
// ---------------------------------------------------------------------------
template <int CTRL>
__device__ __forceinline__ float dpp_add(float x)
{
    int y = __builtin_amdgcn_update_dpp(0, __float_as_int(x), CTRL, 0xf, 0xf, true);
    return x + __int_as_float(y);
}

// sum over an 8-lane group (channel group): xor1, xor2, then half-row mirror
__device__ __forceinline__ float grpsum8(float p)
{
    p = dpp_add<0xB1>(p);   // quad_perm [1,0,3,2] : xor 1
    p = dpp_add<0x4E>(p);   // quad_perm [2,3,0,1] : xor 2
    p = dpp_add<0x141>(p);  // row_half_mirror : other quad of the 8-group
    return p;
}

// 16-lane rowsum (for gemm epilogue replacement not needed; kept for norm? no)
// per-PAIR softmax+accumulate: z,c are this lane's 4 dims; halves = 2 edges.
__device__ __forceinline__ void pair_acc(const float4& z, const float4& c,
                                         float4& a)
{
    float p = z.x * c.x + z.y * c.y + z.z * c.z + z.w * c.w;
    p = grpsum8(p);                     // 32-dim channel dot, |p| <= 1
    float ex = __expf(p);               // group-constant
    float t  = dpp_add<0x128>(ex);      // row_ror:8 -> + other group in 16-row
    float d  = t + __shfl_xor(t, 16);   // + other 16-row of this half
    float w  = ex * __builtin_amdgcn_rcpf(d);
    a.x += w * z.x;  a.y += w * z.y;
    a.z += w * z.z;  a.w += w * z.w;
}

// ---------------------------------------------------------------------------
// GEMM + per-channel L2 normalize (fp32 h) — round-13 v3 (kept).
// ---------------------------------------------------------------------------
__global__ __launch_bounds__(256)
void gemm_norm_kernel(const float* __restrict__ x, const float* __restrict__ W,
                      const float* __restrict__ b, float* __restrict__ h, int n)
{
    __shared__ float WT[32 * 132];    // WT[lc*132 + j] = W[j][l0+lc]

    const int tid  = threadIdx.x;
    const int jc   = tid & 31;
    const int rg   = tid >> 5;
    const int row0 = blockIdx.x * 32;

    float4 bb = ((const float4*)b)[jc];
    float acc[4][4];
    #pragma unroll
    for (int ri = 0; ri < 4; ++ri) {
        acc[ri][0] = bb.x; acc[ri][1] = bb.y; acc[ri][2] = bb.z; acc[ri][3] = bb.w;
    }

    for (int l0 = 0; l0 < 128; l0 += 32) {
        __syncthreads();
        for (int t = 0; t < 16; ++t) {
            int idx = t * 256 + tid;
            int j = idx >> 5, lc = idx & 31;
            WT[lc * 132 + j] = W[j * 128 + l0 + lc];
        }
        __syncthreads();

        #pragma unroll 2
        for (int q = 0; q < 8; ++q) {
            float4 xq[4];
            #pragma unroll
            for (int ri = 0; ri < 4; ++ri) {
                int row = row0 + rg * 4 + ri;
                row = row < n ? row : n - 1;
                xq[ri] = *(const float4*)(x + (size_t)row * 128 + l0 + q * 4);
            }
            #pragma unroll
            for (int k = 0; k < 4; ++k) {
                float4 wt = ((const float4*)(WT + (q * 4 + k) * 132))[jc];
                #pragma unroll
                for (int ri = 0; ri < 4; ++ri) {
                    float xv = (k == 0) ? xq[ri].x : (k == 1) ? xq[ri].y
                             : (k == 2) ? xq[ri].z : xq[ri].w;
                    acc[ri][0] += xv * wt.x;
                    acc[ri][1] += xv * wt.y;
                    acc[ri][2] += xv * wt.z;
                    acc[ri][3] += xv * wt.w;
                }
            }
        }
    }

    #pragma unroll
    for (int ri = 0; ri < 4; ++ri) {
        float ss = acc[ri][0]*acc[ri][0] + acc[ri][1]*acc[ri][1]
                 + acc[ri][2]*acc[ri][2] + acc[ri][3]*acc[ri][3];
        ss += __shfl_xor(ss, 1);
        ss += __shfl_xor(ss, 2);
        ss += __shfl_xor(ss, 4);
        float inv = 1.0f / fmaxf(sqrtf(ss), 1e-12f);
        int row = row0 + rg * 4 + ri;
        if (row < n) {
            float4 o;
            o.x = acc[ri][0]*inv; o.y = acc[ri][1]*inv;
            o.z = acc[ri][2]*inv; o.w = acc[ri][3]*inv;
            ((float4*)(h + (size_t)row * 128))[jc] = o;
        }
    }
}

// ---------------------------------------------------------------------------
// CSR build (verified r12/13)
// ---------------------------------------------------------------------------
__global__ void zero_detect_kernel(int* __restrict__ p, int n,
                                   const int* __restrict__ raw, int* __restrict__ flag)
{
    int i = blockIdx.x * blockDim.x + threadIdx.x;
    if (i < n) p[i] = 0;
    if (i == 0) {
        int all_zero = 1;
        for (int k = 1; k < 64; k += 2)
            if (raw[k] != 0) { all_zero = 0; break; }
        *flag = all_zero;
    }
}

__global__ void hist_kernel(const void* __restrict__ st, long long m, int n,
                            const int* __restrict__ idx64, int* __restrict__ cnt)
{
    long long e = (long long)blockIdx.x * blockDim.x + threadIdx.x;
    if (e < m) {
        int t = load_idx(st, m + e, *idx64);
        if (t >= 0 && t < n) atomicAdd(&cnt[t], 1);
    }
}

__global__ __launch_bounds__(256)
void scan_partial_kernel(const int* __restrict__ cnt, int n, int chunk,
                         int* __restrict__ bsum)
{
    int b = blockIdx.x, t = threadIdx.x;
    int lo = b * chunk, hi = min(lo + chunk, n);
    int s = 0;
    for (int i = lo + t; i < hi; i += 256) s += cnt[i];
    __shared__ int red[256];
    red[t] = s; __syncthreads();
    for (int off = 128; off > 0; off >>= 1) {
        if (t < off) red[t] += red[t + off];
        __syncthreads();
    }
    if (t == 0) bsum[b] = red[0];
}

__global__ __launch_bounds__(256)
void scan_offsets_kernel(const int* __restrict__ bsum, int nb,
                         int* __restrict__ boff, int* __restrict__ total)
{
    __shared__ int lds[256];
    int t = threadIdx.x;
    int v = (t < nb) ? bsum[t] : 0;
    lds[t] = v; __syncthreads();
    for (int off = 1; off < 256; off <<= 1) {
        int u = (t >= off) ? lds[t - off] : 0;
        __syncthreads();
        lds[t] += u;
        __syncthreads();
    }
    if (t < nb) boff[t] = lds[t] - v;
    if (t == 255) *total = lds[255];
}

__global__ __launch_bounds__(256)
void scan_write_kernel(const int* __restrict__ cnt, int n, int chunk,
                       const int* __restrict__ boff, const int* __restrict__ total,
                       int* __restrict__ row_ptr, int* __restrict__ cursor)
{
    int b = blockIdx.x, t = threadIdx.x;
    int lo = b * chunk, hi = min(lo + chunk, n);
    __shared__ int lds[256];
    int run = boff[b];
    for (int base = lo; base < hi; base += 256) {
        int i = base + t;
        int v = (i < hi) ? cnt[i] : 0;
        lds[t] = v; __syncthreads();
        for (int off = 1; off < 256; off <<= 1) {
            int u = (t >= off) ? lds[t - off] : 0;
            __syncthreads();
            lds[t] += u;
            __syncthreads();
        }
        if (i < hi) {
            int excl = run + lds[t] - v;
            row_ptr[i] = excl;
            cursor[i]  = excl;
        }
        run += lds[255];
        __syncthreads();
    }
    if (b == 0 && t == 0) row_ptr[n] = *total;
}

__global__ void scatter_kernel(const void* __restrict__ st, long long m, int n,
                               const int* __restrict__ idx64,
                               int* __restrict__ cursor, int* __restrict__ edge_src)
{
    long long e = (long long)blockIdx.x * blockDim.x + threadIdx.x;
    if (e < m) {
        int is64 = *idx64;
        int t = load_idx(st, m + e, is64);
        int s = load_idx(st, e, is64);
        if (t >= 0 && t < n) {
            int pos = atomicAdd(&cursor[t], 1);
            edge_src[pos] = s;
        }
    }
}

// ---------------------------------------------------------------------------
// Routing v2: one wave per node, TWO edges per wave step.
// Lanes 0-31 = edge A, lanes 32-63 = edge B; 4 dims/lane (float4).
// Channel = 8-lane group (hl>>3). Self-term only in half A; halves'
// partial sums combined via shfl_xor(32) before each norm.
// ---------------------------------------------------------------------------
__global__ __launch_bounds__(64 * WPB)
void route_kernel(const float* __restrict__ h, const int* __restrict__ row_ptr,
                  const int* __restrict__ edge_src, float* __restrict__ out, int n)
{
    __shared__ float4 zls[WPB][CAP][64];

    int wv   = threadIdx.x >> 6;
    int wid  = __builtin_amdgcn_readfirstlane(blockIdx.x * WPB + wv);
    int lane = threadIdx.x & 63;
    int hl   = lane & 31;
    bool loA = lane < 32;
    if (wid >= n) return;

    const float4* __restrict__ h4 = (const float4*)h;
    float4 c4 = h4[(size_t)wid * 32 + hl];

    const int e0  = row_ptr[wid], e1 = row_ptr[wid + 1];
    const int deg = e1 - e0;
    const int np  = (deg + 1) >> 1;          // edge pairs (last may be odd)
    const int ncp = np < CAP ? np : CAP;     // cached pairs

    float4 a4;

    // ---- iteration 0: gather, cache pairs in LDS, compute ----
    a4.x = loA ? c4.x : 0.0f; a4.y = loA ? c4.y : 0.0f;
    a4.z = loA ? c4.z : 0.0f; a4.w = loA ? c4.w : 0.0f;
    for (int j = 0; j < ncp; ++j) {
        int ia = e0 + 2 * j;
        int sa = edge_src[ia];
        int sb = (ia + 1 < e1) ? edge_src[ia + 1] : -1;
        int s  = loA ? sa : sb;
        float4 z = make_float4(0.f, 0.f, 0.f, 0.f);
        if (s >= 0) z = h4[(size_t)s * 32 + hl];
        zls[wv][j][lane] = z;
        pair_acc(z, c4, a4);
    }
    for (int j = ncp; j < np; ++j) {
        int ia = e0 + 2 * j;
        int sa = edge_src[ia];
        int sb = (ia + 1 < e1) ? edge_src[ia + 1] : -1;
        int s  = loA ? sa : sb;
        float4 z = make_float4(0.f, 0.f, 0.f, 0.f);
        if (s >= 0) z = h4[(size_t)s * 32 + hl];
        pair_acc(z, c4, a4);
    }
    {
        a4.x += __shfl_xor(a4.x, 32);
        a4.y += __shfl_xor(a4.y, 32);
        a4.z += __shfl_xor(a4.z, 32);
        a4.w += __shfl_xor(a4.w, 32);
        float ss = a4.x*a4.x + a4.y*a4.y + a4.z*a4.z + a4.w*a4.w;
        ss = grpsum8(ss);
        float inv = __builtin_amdgcn_rcpf(fmaxf(sqrtf(ss), 1e-12f));
        c4.x = a4.x * inv; c4.y = a4.y * inv;
        c4.z = a4.z * inv; c4.w = a4.w * inv;
    }

    // ---- iterations 1..5: replay cached pairs from LDS (+ global tail) ----
    #pragma unroll 1
    for (int it = 1; it < ROUTIT; ++it) {
        a4.x = loA ? c4.x : 0.0f; a4.y = loA ? c4.y : 0.0f;
        a4.z = loA ? c4.z : 0.0f; a4.w = loA ? c4.w : 0.0f;
        #pragma unroll 2
        for (int j = 0; j < ncp; ++j) {
            float4 z = zls[wv][j][lane];
            pair_acc(z, c4, a4);
        }
        for (int j = ncp; j < np; ++j) {
            int ia = e0 + 2 * j;
            int sa = edge_src[ia];
            int sb = (ia + 1 < e1) ? edge_src[ia + 1] : -1;
            int s  = loA ? sa : sb;
            float4 z = make_float4(0.f, 0.f, 0.f, 0.f);
            if (s >= 0) z = h4[(size_t)s * 32 + hl];
            pair_acc(z, c4, a4);
        }
        a4.x += __shfl_xor(a4.x, 32);
        a4.y += __shfl_xor(a4.y, 32);
        a4.z += __shfl_xor(a4.z, 32);
        a4.w += __shfl_xor(a4.w, 32);
        float ss = a4.x*a4.x + a4.y*a4.y + a4.z*a4.z + a4.w*a4.w;
        ss = grpsum8(ss);
        float inv = __builtin_amdgcn_rcpf(fmaxf(sqrtf(ss), 1e-12f));
        c4.x = a4.x * inv; c4.y = a4.y * inv;
        c4.z = a4.z * inv; c4.w = a4.w * inv;
    }

    if (loA)
        ((float4*)out)[(size_t)wid * 32 + hl] = c4;
}

// ---------------------------------------------------------------------------
extern "C" void kernel_launch(void* const* d_in, const int* in_sizes, int n_in,
                              void* d_out, int out_size, void* d_ws, size_t ws_size,
                              hipStream_t stream)
{
    const float* x       = (const float*)d_in[0];
    const void*  src_trg = d_in[1];
    const float* W       = (const float*)d_in[2];
    const float* b       = (const float*)d_in[3];
    float*       out     = (float*)d_out;

    int n = in_sizes[0] / 128;
    long long m = in_sizes[1] / 2;
    int chunk = (n + SCB - 1) / SCB;

    // workspace layout (~59 MB)
    float* h        = (float*)d_ws;                    // n*128 floats (51.2 MB)
    int*   cnt      = (int*)(h + (size_t)n * 128);     // n
    int*   row_ptr  = cnt + n;                         // n+1
    int*   cursor   = row_ptr + (n + 1);               // n
    int*   edge_src = cursor + n;                      // m ints (6.4 MB)
    int*   idx64    = edge_src + m;                    // 1 flag
    int*   bsum     = idx64 + 1;                       // SCB
    int*   boff     = bsum + SCB;                      // SCB
    int*   total    = boff + SCB;                      // 1

    hipLaunchKernelGGL(gemm_norm_kernel, dim3((n + 31) / 32), dim3(256), 0, stream,
                       x, W, b, h, n);
    hipLaunchKernelGGL(zero_detect_kernel, dim3((n + 255) / 256), dim3(256), 0, stream,
                       cnt, n, (const int*)src_trg, idx64);
    hipLaunchKernelGGL(hist_kernel, dim3((int)((m + 255) / 256)), dim3(256), 0, stream,
                       src_trg, m, n, idx64, cnt);
    hipLaunchKernelGGL(scan_partial_kernel, dim3(SCB), dim3(256), 0, stream,
                       cnt, n, chunk, bsum);
    hipLaunchKernelGGL(scan_offsets_kernel, dim3(1), dim3(256), 0, stream,
                       bsum, SCB, boff, total);
    hipLaunchKernelGGL(scan_write_kernel, dim3(SCB), dim3(256), 0, stream,
                       cnt, n, chunk, boff, total, row_ptr, cursor);
    hipLaunchKernelGGL(scatter_kernel, dim3((int)((m + 255) / 256)), dim3(256), 0, stream,
                       src_trg, m, n, idx64, cursor, edge_src);
    hipLaunchKernelGGL(route_kernel, dim3((n + WPB - 1) / WPB), dim3(64 * WPB), 0, stream,
                       h, row_ptr, edge_src, out, n);
}

// Round 15
// 549.353 us; speedup vs baseline: 1.2158x; 1.1100x over previous
//
#include <hip/hip_runtime.h>
#include <math.h>

#define ROUTIT 6
#define CAPQ 5   // cached quartet-steps per wave (20 edges); 2 waves * 5 * 2KB = 20 KB/block
#define WPB 2    // waves per block in route_kernel
#define SCB 256  // scan blocks

__device__ __forceinline__ int load_idx(const void* p, long long i, int is64)
{
    if (is64) return (int)((const long long*)p)[i];
    return ((const int*)p)[i];
}

// ---------------------------------------------------------------------------
// DPP helpers (VALU pipe) — dpp_add verified r8-14.
// ---------------------------------------------------------------------------
template <int CTRL>
__device__ __forceinline__ float dpp_add(float x)
{
    int y = __builtin_amdgcn_update_dpp(0, __float_as_int(x), CTRL, 0xf, 0xf, true);
    return x + __int_as_float(y);
}

// sum over a 4-lane group (one channel's 32 dims at 8 dims/lane)
__device__ __forceinline__ float grpsum4(float p)
{
    p = dpp_add<0xB1>(p);   // quad_perm [1,0,3,2] : xor 1
    p = dpp_add<0x4E>(p);   // quad_perm [2,3,0,1] : xor 2
    return p;
}

// sum of the four 4-lane-group values within a 16-row (input group-constant)
__device__ __forceinline__ float rowtotal16(float x)
{
    x = dpp_add<0x124>(x);  // row_ror:4  : + adjacent group
    x = dpp_add<0x128>(x);  // row_ror:8  : + the other pair
    return x;
}

// x[l] + x[l^16]: permlane16_swap builtin (VALU). With equal operands the
// pair-sum r[0]+r[1] is invariant to the swap pairing convention.
// (r6/7 bug was hand-asm register aliasing, not instruction semantics.)
__device__ __forceinline__ float sum_x16(float x)
{
#if __has_builtin(__builtin_amdgcn_permlane16_swap)
    unsigned u = __float_as_uint(x);
    auto r = __builtin_amdgcn_permlane16_swap(u, u, false, false);
    return __uint_as_float(r[0]) + __uint_as_float(r[1]);
#else
    return x + __shfl_xor(x, 16);
#endif
}

__device__ __forceinline__ float sum_x32(float x)
{
#if __has_builtin(__builtin_amdgcn_permlane32_swap)
    unsigned u = __float_as_uint(x);
    auto r = __builtin_amdgcn_permlane32_swap(u, u, false, false);
    return __uint_as_float(r[0]) + __uint_as_float(r[1]);
#else
    return x + __shfl_xor(x, 32);
#endif
}

// per-quartet-step: this lane's edge is its 16-row; z,c = 8 dims (2 float4)
__device__ __forceinline__ void quad_acc(const float4& zA, const float4& zB,
                                         const float4& cA, const float4& cB,
                                         float4& aA, float4& aB)
{
    float p = zA.x*cA.x + zA.y*cA.y + zA.z*cA.z + zA.w*cA.w
            + zB.x*cB.x + zB.y*cB.y + zB.z*cB.z + zB.w*cB.w;
    p = grpsum4(p);                     // 32-dim channel dot, |p| <= 1
    float ex = __expf(p);
    float d  = rowtotal16(ex);          // softmax denom (4 channels, in-row)
    float w  = ex * __builtin_amdgcn_rcpf(d);
    aA.x += w * zA.x;  aA.y += w * zA.y;  aA.z += w * zA.z;  aA.w += w * zA.w;
    aB.x += w * zB.x;  aB.y += w * zB.y;  aB.z += w * zB.z;  aB.w += w * zB.w;
}

// ---------------------------------------------------------------------------
// GEMM + per-channel L2 normalize (fp32 h) — round-13 v3 (kept).
// ---------------------------------------------------------------------------
__global__ __launch_bounds__(256)
void gemm_norm_kernel(const float* __restrict__ x, const float* __restrict__ W,
                      const float* __restrict__ b, float* __restrict__ h, int n)
{
    __shared__ float WT[32 * 132];    // WT[lc*132 + j] = W[j][l0+lc]

    const int tid  = threadIdx.x;
    const int jc   = tid & 31;
    const int rg   = tid >> 5;
    const int row0 = blockIdx.x * 32;

    float4 bb = ((const float4*)b)[jc];
    float acc[4][4];
    #pragma unroll
    for (int ri = 0; ri < 4; ++ri) {
        acc[ri][0] = bb.x; acc[ri][1] = bb.y; acc[ri][2] = bb.z; acc[ri][3] = bb.w;
    }

    for (int l0 = 0; l0 < 128; l0 += 32) {
        __syncthreads();
        for (int t = 0; t < 16; ++t) {
            int idx = t * 256 + tid;
            int j = idx >> 5, lc = idx & 31;
            WT[lc * 132 + j] = W[j * 128 + l0 + lc];
        }
        __syncthreads();

        #pragma unroll 2
        for (int q = 0; q < 8; ++q) {
            float4 xq[4];
            #pragma unroll
            for (int ri = 0; ri < 4; ++ri) {
                int row = row0 + rg * 4 + ri;
                row = row < n ? row : n - 1;
                xq[ri] = *(const float4*)(x + (size_t)row * 128 + l0 + q * 4);
            }
            #pragma unroll
            for (int k = 0; k < 4; ++k) {
                float4 wt = ((const float4*)(WT + (q * 4 + k) * 132))[jc];
                #pragma unroll
                for (int ri = 0; ri < 4; ++ri) {
                    float xv = (k == 0) ? xq[ri].x : (k == 1) ? xq[ri].y
                             : (k == 2) ? xq[ri].z : xq[ri].w;
                    acc[ri][0] += xv * wt.x;
                    acc[ri][1] += xv * wt.y;
                    acc[ri][2] += xv * wt.z;
                    acc[ri][3] += xv * wt.w;
                }
            }
        }
    }

    #pragma unroll
    for (int ri = 0; ri < 4; ++ri) {
        float ss = acc[ri][0]*acc[ri][0] + acc[ri][1]*acc[ri][1]
                 + acc[ri][2]*acc[ri][2] + acc[ri][3]*acc[ri][3];
        ss += __shfl_xor(ss, 1);
        ss += __shfl_xor(ss, 2);
        ss += __shfl_xor(ss, 4);
        float inv = 1.0f / fmaxf(sqrtf(ss), 1e-12f);
        int row = row0 + rg * 4 + ri;
        if (row < n) {
            float4 o;
            o.x = acc[ri][0]*inv; o.y = acc[ri][1]*inv;
            o.z = acc[ri][2]*inv; o.w = acc[ri][3]*inv;
            ((float4*)(h + (size_t)row * 128))[jc] = o;
        }
    }
}

// ---------------------------------------------------------------------------
// CSR build (verified r12-14)
// ---------------------------------------------------------------------------
__global__ void zero_detect_kernel(int* __restrict__ p, int n,
                                   const int* __restrict__ raw, int* __restrict__ flag)
{
    int i = blockIdx.x * blockDim.x + threadIdx.x;
    if (i < n) p[i] = 0;
    if (i == 0) {
        int all_zero = 1;
        for (int k = 1; k < 64; k += 2)
            if (raw[k] != 0) { all_zero = 0; break; }
        *flag = all_zero;
    }
}

__global__ void hist_kernel(const void* __restrict__ st, long long m, int n,
                            const int* __restrict__ idx64, int* __restrict__ cnt)
{
    long long e = (long long)blockIdx.x * blockDim.x + threadIdx.x;
    if (e < m) {
        int t = load_idx(st, m + e, *idx64);
        if (t >= 0 && t < n) atomicAdd(&cnt[t], 1);
    }
}

__global__ __launch_bounds__(256)
void scan_partial_kernel(const int* __restrict__ cnt, int n, int chunk,
                         int* __restrict__ bsum)
{
    int b = blockIdx.x, t = threadIdx.x;
    int lo = b * chunk, hi = min(lo + chunk, n);
    int s = 0;
    for (int i = lo + t; i < hi; i += 256) s += cnt[i];
    __shared__ int red[256];
    red[t] = s; __syncthreads();
    for (int off = 128; off > 0; off >>= 1) {
        if (t < off) red[t] += red[t + off];
        __syncthreads();
    }
    if (t == 0) bsum[b] = red[0];
}

__global__ __launch_bounds__(256)
void scan_offsets_kernel(const int* __restrict__ bsum, int nb,
                         int* __restrict__ boff, int* __restrict__ total)
{
    __shared__ int lds[256];
    int t = threadIdx.x;
    int v = (t < nb) ? bsum[t] : 0;
    lds[t] = v; __syncthreads();
    for (int off = 1; off < 256; off <<= 1) {
        int u = (t >= off) ? lds[t - off] : 0;
        __syncthreads();
        lds[t] += u;
        __syncthreads();
    }
    if (t < nb) boff[t] = lds[t] - v;
    if (t == 255) *total = lds[255];
}

__global__ __launch_bounds__(256)
void scan_write_kernel(const int* __restrict__ cnt, int n, int chunk,
                       const int* __restrict__ boff, const int* __restrict__ total,
                       int* __restrict__ row_ptr, int* __restrict__ cursor)
{
    int b = blockIdx.x, t = threadIdx.x;
    int lo = b * chunk, hi = min(lo + chunk, n);
    __shared__ int lds[256];
    int run = boff[b];
    for (int base = lo; base < hi; base += 256) {
        int i = base + t;
        int v = (i < hi) ? cnt[i] : 0;
        lds[t] = v; __syncthreads();
        for (int off = 1; off < 256; off <<= 1) {
            int u = (t >= off) ? lds[t - off] : 0;
            __syncthreads();
            lds[t] += u;
            __syncthreads();
        }
        if (i < hi) {
            int excl = run + lds[t] - v;
            row_ptr[i] = excl;
            cursor[i]  = excl;
        }
        run += lds[255];
        __syncthreads();
    }
    if (b == 0 && t == 0) row_ptr[n] = *total;
}

__global__ void scatter_kernel(const void* __restrict__ st, long long m, int n,
                               const int* __restrict__ idx64,
                               int* __restrict__ cursor, int* __restrict__ edge_src)
{
    long long e = (long long)blockIdx.x * blockDim.x + threadIdx.x;
    if (e < m) {
        int is64 = *idx64;
        int t = load_idx(st, m + e, is64);
        int s = load_idx(st, e, is64);
        if (t >= 0 && t < n) {
            int pos = atomicAdd(&cursor[t], 1);
            edge_src[pos] = s;
        }
    }
}

// ---------------------------------------------------------------------------
// Routing v3: one wave per node, FOUR edges per wave step (one per 16-row),
// 8 dims/lane. Per-edge cross-lane work is pure DPP (in-row); cross-row
// combine once per iteration via permlane swaps (VALU). LDS z-cache in SoA
// (conflict-free b128). Self-term lives in row 0 only.
// ---------------------------------------------------------------------------
__global__ __launch_bounds__(64 * WPB)
void route_kernel(const float* __restrict__ h, const int* __restrict__ row_ptr,
                  const int* __restrict__ edge_src, float* __restrict__ out, int n)
{
    __shared__ float4 zlsA[WPB][CAPQ][64];
    __shared__ float4 zlsB[WPB][CAPQ][64];

    int wv   = threadIdx.x >> 6;
    int wid  = __builtin_amdgcn_readfirstlane(blockIdx.x * WPB + wv);
    int lane = threadIdx.x & 63;
    int row  = lane >> 4;     // which edge of the quartet
    int rl   = lane & 15;     // lane within row: dims [rl*8, rl*8+8)
    if (wid >= n) return;

    const float4* __restrict__ h4 = (const float4*)h;
    float4 cA = h4[(size_t)wid * 32 + rl * 2];
    float4 cB = h4[(size_t)wid * 32 + rl * 2 + 1];

    const int e0  = row_ptr[wid], e1 = row_ptr[wid + 1];
    const int deg = e1 - e0;
    const int np  = (deg + 3) >> 2;            // quartet steps
    const int ncp = np < CAPQ ? np : CAPQ;     // cached steps
    const float selfm = (row == 0) ? 1.0f : 0.0f;

    float4 aA, aB;

    // ---- iteration 0: gather, cache (SoA), compute ----
    aA.x = cA.x*selfm; aA.y = cA.y*selfm; aA.z = cA.z*selfm; aA.w = cA.w*selfm;
    aB.x = cB.x*selfm; aB.y = cB.y*selfm; aB.z = cB.z*selfm; aB.w = cB.w*selfm;
    for (int j = 0; j < np; ++j) {
        int ei = e0 + 4 * j + row;
        int s  = (ei < e1) ? edge_src[ei] : -1;
        float4 zA = make_float4(0.f,0.f,0.f,0.f);
        float4 zB = make_float4(0.f,0.f,0.f,0.f);
        if (s >= 0) {
            zA = h4[(size_t)s * 32 + rl * 2];
            zB = h4[(size_t)s * 32 + rl * 2 + 1];
        }
        if (j < ncp) {
            zlsA[wv][j][lane] = zA;
            zlsB[wv][j][lane] = zB;
        }
        quad_acc(zA, zB, cA, cB, aA, aB);
    }
    {
        aA.x = sum_x32(sum_x16(aA.x)); aA.y = sum_x32(sum_x16(aA.y));
        aA.z = sum_x32(sum_x16(aA.z)); aA.w = sum_x32(sum_x16(aA.w));
        aB.x = sum_x32(sum_x16(aB.x)); aB.y = sum_x32(sum_x16(aB.y));
        aB.z = sum_x32(sum_x16(aB.z)); aB.w = sum_x32(sum_x16(aB.w));
        float ss = aA.x*aA.x + aA.y*aA.y + aA.z*aA.z + aA.w*aA.w
                 + aB.x*aB.x + aB.y*aB.y + aB.z*aB.z + aB.w*aB.w;
        ss = grpsum4(ss);
        float inv = __builtin_amdgcn_rcpf(fmaxf(sqrtf(ss), 1e-12f));
        cA.x = aA.x*inv; cA.y = aA.y*inv; cA.z = aA.z*inv; cA.w = aA.w*inv;
        cB.x = aB.x*inv; cB.y = aB.y*inv; cB.z = aB.z*inv; cB.w = aB.w*inv;
    }

    // ---- iterations 1..5: replay cached steps from LDS (+ global tail) ----
    #pragma unroll 1
    for (int it = 1; it < ROUTIT; ++it) {
        aA.x = cA.x*selfm; aA.y = cA.y*selfm; aA.z = cA.z*selfm; aA.w = cA.w*selfm;
        aB.x = cB.x*selfm; aB.y = cB.y*selfm; aB.z = cB.z*selfm; aB.w = cB.w*selfm;
        #pragma unroll 2
        for (int j = 0; j < ncp; ++j) {
            float4 zA = zlsA[wv][j][lane];
            float4 zB = zlsB[wv][j][lane];
            quad_acc(zA, zB, cA, cB, aA, aB);
        }
        for (int j = ncp; j < np; ++j) {
            int ei = e0 + 4 * j + row;
            int s  = (ei < e1) ? edge_src[ei] : -1;
            float4 zA = make_float4(0.f,0.f,0.f,0.f);
            float4 zB = make_float4(0.f,0.f,0.f,0.f);
            if (s >= 0) {
                zA = h4[(size_t)s * 32 + rl * 2];
                zB = h4[(size_t)s * 32 + rl * 2 + 1];
            }
            quad_acc(zA, zB, cA, cB, aA, aB);
        }
        aA.x = sum_x32(sum_x16(aA.x)); aA.y = sum_x32(sum_x16(aA.y));
        aA.z = sum_x32(sum_x16(aA.z)); aA.w = sum_x32(sum_x16(aA.w));
        aB.x = sum_x32(sum_x16(aB.x)); aB.y = sum_x32(sum_x16(aB.y));
        aB.z = sum_x32(sum_x16(aB.z)); aB.w = sum_x32(sum_x16(aB.w));
        float ss = aA.x*aA.x + aA.y*aA.y + aA.z*aA.z + aA.w*aA.w
                 + aB.x*aB.x + aB.y*aB.y + aB.z*aB.z + aB.w*aB.w;
        ss = grpsum4(ss);
        float inv = __builtin_amdgcn_rcpf(fmaxf(sqrtf(ss), 1e-12f));
        cA.x = aA.x*inv; cA.y = aA.y*inv; cA.z = aA.z*inv; cA.w = aA.w*inv;
        cB.x = aB.x*inv; cB.y = aB.y*inv; cB.z = aB.z*inv; cB.w = aB.w*inv;
    }

    if (row == 0) {
        ((float4*)out)[(size_t)wid * 32 + rl * 2]     = cA;
        ((float4*)out)[(size_t)wid * 32 + rl * 2 + 1] = cB;
    }
}

// ---------------------------------------------------------------------------
extern "C" void kernel_launch(void* const* d_in, const int* in_sizes, int n_in,
                              void* d_out, int out_size, void* d_ws, size_t ws_size,
                              hipStream_t stream)
{
    const float* x       = (const float*)d_in[0];
    const void*  src_trg = d_in[1];
    const float* W       = (const float*)d_in[2];
    const float* b       = (const float*)d_in[3];
    float*       out     = (float*)d_out;

    int n = in_sizes[0] / 128;
    long long m = in_sizes[1] / 2;
    int chunk = (n + SCB - 1) / SCB;

    // workspace layout (~59 MB)
    float* h        = (float*)d_ws;                    // n*128 floats (51.2 MB)
    int*   cnt      = (int*)(h + (size_t)n * 128);     // n
    int*   row_ptr  = cnt + n;                         // n+1
    int*   cursor   = row_ptr + (n + 1);               // n
    int*   edge_src = cursor + n;                      // m ints (6.4 MB)
    int*   idx64    = edge_src + m;                    // 1 flag
    int*   bsum     = idx64 + 1;                       // SCB
    int*   boff     = bsum + SCB;                      // SCB
    int*   total    = boff + SCB;                      // 1

    hipLaunchKernelGGL(gemm_norm_kernel, dim3((n + 31) / 32), dim3(256), 0, stream,
                       x, W, b, h, n);
    hipLaunchKernelGGL(zero_detect_kernel, dim3((n + 255) / 256), dim3(256), 0, stream,
                       cnt, n, (const int*)src_trg, idx64);
    hipLaunchKernelGGL(hist_kernel, dim3((int)((m + 255) / 256)), dim3(256), 0, stream,
                       src_trg, m, n, idx64, cnt);
    hipLaunchKernelGGL(scan_partial_kernel, dim3(SCB), dim3(256), 0, stream,
                       cnt, n, chunk, bsum);
    hipLaunchKernelGGL(scan_offsets_kernel, dim3(1), dim3(256), 0, stream,
                       bsum, SCB, boff, total);
    hipLaunchKernelGGL(scan_write_kernel, dim3(SCB), dim3(256), 0, stream,
                       cnt, n, chunk, boff, total, row_ptr, cursor);
    hipLaunchKernelGGL(scatter_kernel, dim3((int)((m + 255) / 256)), dim3(256), 0, stream,
                       src_trg, m, n, idx64, cursor, edge_src);
    hipLaunchKernelGGL(route_kernel, dim3((n + WPB - 1) / WPB), dim3(64 * WPB), 0, stream,
                       h, row_ptr, edge_src, out, n);
}

// Round 16
// 543.441 us; speedup vs baseline: 1.2291x; 1.0109x over previous
//
#include <hip/hip_runtime.h>
#include <math.h>

#define ROUTIT 6
#define CAPQ 5   // cached quartet-steps per wave; 2 waves * 5 * 2KB = 20 KB/block
#define WPB 2    // waves per block in route_kernel
#define SCB 256  // scan blocks

__device__ __forceinline__ int load_idx(const void* p, long long i, int is64)
{
    if (is64) return (int)((const long long*)p)[i];
    return ((const int*)p)[i];
}

// ---------------------------------------------------------------------------
// DPP helpers (VALU pipe) — verified r8-15.
// ---------------------------------------------------------------------------
template <int CTRL>
__device__ __forceinline__ float dpp_add(float x)
{
    int y = __builtin_amdgcn_update_dpp(0, __float_as_int(x), CTRL, 0xf, 0xf, true);
    return x + __int_as_float(y);
}

// sum over a 4-lane group (one channel's 32 dims at 8 dims/lane)
__device__ __forceinline__ float grpsum4(float p)
{
    p = dpp_add<0xB1>(p);   // quad_perm xor1
    p = dpp_add<0x4E>(p);   // quad_perm xor2
    return p;
}

// sum of the four 4-lane-group values within a 16-row (input group-constant)
__device__ __forceinline__ float rowtotal16(float x)
{
    x = dpp_add<0x124>(x);  // row_ror:4
    x = dpp_add<0x128>(x);  // row_ror:8
    return x;
}

// x[l] + x[l^16] / x[l] + x[l^32] — permlane swap builtins (verified r15)
__device__ __forceinline__ float sum_x16(float x)
{
#if __has_builtin(__builtin_amdgcn_permlane16_swap)
    unsigned u = __float_as_uint(x);
    auto r = __builtin_amdgcn_permlane16_swap(u, u, false, false);
    return __uint_as_float(r[0]) + __uint_as_float(r[1]);
#else
    return x + __shfl_xor(x, 16);
#endif
}

__device__ __forceinline__ float sum_x32(float x)
{
#if __has_builtin(__builtin_amdgcn_permlane32_swap)
    unsigned u = __float_as_uint(x);
    auto r = __builtin_amdgcn_permlane32_swap(u, u, false, false);
    return __uint_as_float(r[0]) + __uint_as_float(r[1]);
#else
    return x + __shfl_xor(x, 32);
#endif
}

// per-quartet-step: this lane's edge is its 16-row; z,c = 8 dims (2 float4).
// Dummy edges (z = 0) are inert: p=0 -> ex=1 enters only this row's own
// denominator; w*z = 0.
__device__ __forceinline__ void quad_acc(const float4& zA, const float4& zB,
                                         const float4& cA, const float4& cB,
                                         float4& aA, float4& aB)
{
    float p = zA.x*cA.x + zA.y*cA.y + zA.z*cA.z + zA.w*cA.w
            + zB.x*cB.x + zB.y*cB.y + zB.z*cB.z + zB.w*cB.w;
    p = grpsum4(p);                     // 32-dim channel dot, |p| <= 1
    float ex = __expf(p);
    float d  = rowtotal16(ex);          // softmax denom (4 channels, in-row)
    float w  = ex * __builtin_amdgcn_rcpf(d);
    aA.x += w * zA.x;  aA.y += w * zA.y;  aA.z += w * zA.z;  aA.w += w * zA.w;
    aB.x += w * zB.x;  aB.y += w * zB.y;  aB.z += w * zB.z;  aB.w += w * zB.w;
}

// ---------------------------------------------------------------------------
// GEMM + per-channel L2 normalize (fp32 h) — round-13 v3 (kept).
// ---------------------------------------------------------------------------
__global__ __launch_bounds__(256)
void gemm_norm_kernel(const float* __restrict__ x, const float* __restrict__ W,
                      const float* __restrict__ b, float* __restrict__ h, int n)
{
    __shared__ float WT[32 * 132];    // WT[lc*132 + j] = W[j][l0+lc]

    const int tid  = threadIdx.x;
    const int jc   = tid & 31;
    const int rg   = tid >> 5;
    const int row0 = blockIdx.x * 32;

    float4 bb = ((const float4*)b)[jc];
    float acc[4][4];
    #pragma unroll
    for (int ri = 0; ri < 4; ++ri) {
        acc[ri][0] = bb.x; acc[ri][1] = bb.y; acc[ri][2] = bb.z; acc[ri][3] = bb.w;
    }

    for (int l0 = 0; l0 < 128; l0 += 32) {
        __syncthreads();
        for (int t = 0; t < 16; ++t) {
            int idx = t * 256 + tid;
            int j = idx >> 5, lc = idx & 31;
            WT[lc * 132 + j] = W[j * 128 + l0 + lc];
        }
        __syncthreads();

        #pragma unroll 2
        for (int q = 0; q < 8; ++q) {
            float4 xq[4];
            #pragma unroll
            for (int ri = 0; ri < 4; ++ri) {
                int row = row0 + rg * 4 + ri;
                row = row < n ? row : n - 1;
                xq[ri] = *(const float4*)(x + (size_t)row * 128 + l0 + q * 4);
            }
            #pragma unroll
            for (int k = 0; k < 4; ++k) {
                float4 wt = ((const float4*)(WT + (q * 4 + k) * 132))[jc];
                #pragma unroll
                for (int ri = 0; ri < 4; ++ri) {
                    float xv = (k == 0) ? xq[ri].x : (k == 1) ? xq[ri].y
                             : (k == 2) ? xq[ri].z : xq[ri].w;
                    acc[ri][0] += xv * wt.x;
                    acc[ri][1] += xv * wt.y;
                    acc[ri][2] += xv * wt.z;
                    acc[ri][3] += xv * wt.w;
                }
            }
        }
    }

    #pragma unroll
    for (int ri = 0; ri < 4; ++ri) {
        float ss = acc[ri][0]*acc[ri][0] + acc[ri][1]*acc[ri][1]
                 + acc[ri][2]*acc[ri][2] + acc[ri][3]*acc[ri][3];
        ss += __shfl_xor(ss, 1);
        ss += __shfl_xor(ss, 2);
        ss += __shfl_xor(ss, 4);
        float inv = 1.0f / fmaxf(sqrtf(ss), 1e-12f);
        int row = row0 + rg * 4 + ri;
        if (row < n) {
            float4 o;
            o.x = acc[ri][0]*inv; o.y = acc[ri][1]*inv;
            o.z = acc[ri][2]*inv; o.w = acc[ri][3]*inv;
            ((float4*)(h + (size_t)row * 128))[jc] = o;
        }
    }
}

// ---------------------------------------------------------------------------
// prep: zero cnt, zero h row n (the dummy row), pre-fill padded edge_src
// with n, detect idx dtype. All independent; grid-stride over padcap.
// ---------------------------------------------------------------------------
__global__ void prep_kernel(int* __restrict__ cnt, int n,
                            float* __restrict__ h,
                            int* __restrict__ edge_src, long long padcap,
                            const int* __restrict__ raw, int* __restrict__ flag)
{
    long long i = (long long)blockIdx.x * blockDim.x + threadIdx.x;
    long long stride = (long long)gridDim.x * blockDim.x;
    for (long long k = i; k < padcap; k += stride) {
        if (k < n) cnt[k] = 0;
        if (k < 128) h[(size_t)n * 128 + k] = 0.0f;
        edge_src[k] = n;
    }
    if (i == 0) {
        int all_zero = 1;
        for (int k = 1; k < 64; k += 2)
            if (raw[k] != 0) { all_zero = 0; break; }
        *flag = all_zero;
    }
}

__global__ void hist_kernel(const void* __restrict__ st, long long m, int n,
                            const int* __restrict__ idx64, int* __restrict__ cnt)
{
    long long e = (long long)blockIdx.x * blockDim.x + threadIdx.x;
    if (e < m) {
        int t = load_idx(st, m + e, *idx64);
        if (t >= 0 && t < n) atomicAdd(&cnt[t], 1);
    }
}

// ---- 3-phase parallel scan over PADDED degrees (pad4) ----
__global__ __launch_bounds__(256)
void scan_partial_kernel(const int* __restrict__ cnt, int n, int chunk,
                         int* __restrict__ bsum)
{
    int b = blockIdx.x, t = threadIdx.x;
    int lo = b * chunk, hi = min(lo + chunk, n);
    int s = 0;
    for (int i = lo + t; i < hi; i += 256) s += (cnt[i] + 3) & ~3;
    __shared__ int red[256];
    red[t] = s; __syncthreads();
    for (int off = 128; off > 0; off >>= 1) {
        if (t < off) red[t] += red[t + off];
        __syncthreads();
    }
    if (t == 0) bsum[b] = red[0];
}

__global__ __launch_bounds__(256)
void scan_offsets_kernel(const int* __restrict__ bsum, int nb,
                         int* __restrict__ boff, int* __restrict__ total)
{
    __shared__ int lds[256];
    int t = threadIdx.x;
    int v = (t < nb) ? bsum[t] : 0;
    lds[t] = v; __syncthreads();
    for (int off = 1; off < 256; off <<= 1) {
        int u = (t >= off) ? lds[t - off] : 0;
        __syncthreads();
        lds[t] += u;
        __syncthreads();
    }
    if (t < nb) boff[t] = lds[t] - v;
    if (t == 255) *total = lds[255];
}

__global__ __launch_bounds__(256)
void scan_write_kernel(const int* __restrict__ cnt, int n, int chunk,
                       const int* __restrict__ boff, const int* __restrict__ total,
                       int* __restrict__ row_ptr, int* __restrict__ cursor)
{
    int b = blockIdx.x, t = threadIdx.x;
    int lo = b * chunk, hi = min(lo + chunk, n);
    __shared__ int lds[256];
    int run = boff[b];
    for (int base = lo; base < hi; base += 256) {
        int i = base + t;
        int v = (i < hi) ? ((cnt[i] + 3) & ~3) : 0;
        lds[t] = v; __syncthreads();
        for (int off = 1; off < 256; off <<= 1) {
            int u = (t >= off) ? lds[t - off] : 0;
            __syncthreads();
            lds[t] += u;
            __syncthreads();
        }
        if (i < hi) {
            int excl = run + lds[t] - v;
            row_ptr[i] = excl;
            cursor[i]  = excl;
        }
        run += lds[255];
        __syncthreads();
    }
    if (b == 0 && t == 0) row_ptr[n] = *total;
}

__global__ void scatter_kernel(const void* __restrict__ st, long long m, int n,
                               const int* __restrict__ idx64,
                               int* __restrict__ cursor, int* __restrict__ edge_src)
{
    long long e = (long long)blockIdx.x * blockDim.x + threadIdx.x;
    if (e < m) {
        int is64 = *idx64;
        int t = load_idx(st, m + e, is64);
        int s = load_idx(st, e, is64);
        if (t >= 0 && t < n) {
            int pos = atomicAdd(&cursor[t], 1);
            edge_src[pos] = s;
        }
    }
}

// ---------------------------------------------------------------------------
// Routing v4: quartet layout (4 edges/step, 8 dims/lane) on a PADDED CSR —
// inner loop is branch-free: unconditional edge_src + h reads (dummy edges
// point at the zero row n and contribute nothing).
// ---------------------------------------------------------------------------
__global__ __launch_bounds__(64 * WPB)
void route_kernel(const float* __restrict__ h, const int* __restrict__ row_ptr,
                  const int* __restrict__ edge_src, float* __restrict__ out, int n)
{
    __shared__ float4 zlsA[WPB][CAPQ][64];
    __shared__ float4 zlsB[WPB][CAPQ][64];

    int wv   = threadIdx.x >> 6;
    int wid  = __builtin_amdgcn_readfirstlane(blockIdx.x * WPB + wv);
    int lane = threadIdx.x & 63;
    int row  = lane >> 4;     // which edge of the quartet
    int rl   = lane & 15;     // lane within row: dims [rl*8, rl*8+8)
    if (wid >= n) return;

    const float4* __restrict__ h4 = (const float4*)h;
    float4 cA = h4[(size_t)wid * 32 + rl * 2];
    float4 cB = h4[(size_t)wid * 32 + rl * 2 + 1];

    const int e0  = row_ptr[wid];
    const int np  = (row_ptr[wid + 1] - e0) >> 2;   // padded quartet steps
    const int ncp = np < CAPQ ? np : CAPQ;
    const float selfm = (row == 0) ? 1.0f : 0.0f;

    float4 aA, aB;

    // ---- iteration 0: gather, cache (SoA), compute — branch-free loads ----
    aA.x = cA.x*selfm; aA.y = cA.y*selfm; aA.z = cA.z*selfm; aA.w = cA.w*selfm;
    aB.x = cB.x*selfm; aB.y = cB.y*selfm; aB.z = cB.z*selfm; aB.w = cB.w*selfm;
    for (int j = 0; j < np; ++j) {
        int s = edge_src[e0 + 4 * j + row];
        float4 zA = h4[(size_t)s * 32 + rl * 2];
        float4 zB = h4[(size_t)s * 32 + rl * 2 + 1];
        if (j < ncp) {
            zlsA[wv][j][lane] = zA;
            zlsB[wv][j][lane] = zB;
        }
        quad_acc(zA, zB, cA, cB, aA, aB);
    }
    {
        aA.x = sum_x32(sum_x16(aA.x)); aA.y = sum_x32(sum_x16(aA.y));
        aA.z = sum_x32(sum_x16(aA.z)); aA.w = sum_x32(sum_x16(aA.w));
        aB.x = sum_x32(sum_x16(aB.x)); aB.y = sum_x32(sum_x16(aB.y));
        aB.z = sum_x32(sum_x16(aB.z)); aB.w = sum_x32(sum_x16(aB.w));
        float ss = aA.x*aA.x + aA.y*aA.y + aA.z*aA.z + aA.w*aA.w
                 + aB.x*aB.x + aB.y*aB.y + aB.z*aB.z + aB.w*aB.w;
        ss = grpsum4(ss);
        float inv = __builtin_amdgcn_rcpf(fmaxf(sqrtf(ss), 1e-12f));
        cA.x = aA.x*inv; cA.y = aA.y*inv; cA.z = aA.z*inv; cA.w = aA.w*inv;
        cB.x = aB.x*inv; cB.y = aB.y*inv; cB.z = aB.z*inv; cB.w = aB.w*inv;
    }

    // ---- iterations 1..5: replay cached steps from LDS (+ global tail) ----
    #pragma unroll 1
    for (int it = 1; it < ROUTIT; ++it) {
        aA.x = cA.x*selfm; aA.y = cA.y*selfm; aA.z = cA.z*selfm; aA.w = cA.w*selfm;
        aB.x = cB.x*selfm; aB.y = cB.y*selfm; aB.z = cB.z*selfm; aB.w = cB.w*selfm;
        #pragma unroll 2
        for (int j = 0; j < ncp; ++j) {
            float4 zA = zlsA[wv][j][lane];
            float4 zB = zlsB[wv][j][lane];
            quad_acc(zA, zB, cA, cB, aA, aB);
        }
        for (int j = ncp; j < np; ++j) {
            int s = edge_src[e0 + 4 * j + row];
            float4 zA = h4[(size_t)s * 32 + rl * 2];
            float4 zB = h4[(size_t)s * 32 + rl * 2 + 1];
            quad_acc(zA, zB, cA, cB, aA, aB);
        }
        aA.x = sum_x32(sum_x16(aA.x)); aA.y = sum_x32(sum_x16(aA.y));
        aA.z = sum_x32(sum_x16(aA.z)); aA.w = sum_x32(sum_x16(aA.w));
        aB.x = sum_x32(sum_x16(aB.x)); aB.y = sum_x32(sum_x16(aB.y));
        aB.z = sum_x32(sum_x16(aB.z)); aB.w = sum_x32(sum_x16(aB.w));
        float ss = aA.x*aA.x + aA.y*aA.y + aA.z*aA.z + aA.w*aA.w
                 + aB.x*aB.x + aB.y*aB.y + aB.z*aB.z + aB.w*aB.w;
        ss = grpsum4(ss);
        float inv = __builtin_amdgcn_rcpf(fmaxf(sqrtf(ss), 1e-12f));
        cA.x = aA.x*inv; cA.y = aA.y*inv; cA.z = aA.z*inv; cA.w = aA.w*inv;
        cB.x = aB.x*inv; cB.y = aB.y*inv; cB.z = aB.z*inv; cB.w = aB.w*inv;
    }

    if (row == 0) {
        ((float4*)out)[(size_t)wid * 32 + rl * 2]     = cA;
        ((float4*)out)[(size_t)wid * 32 + rl * 2 + 1] = cB;
    }
}

// ---------------------------------------------------------------------------
extern "C" void kernel_launch(void* const* d_in, const int* in_sizes, int n_in,
                              void* d_out, int out_size, void* d_ws, size_t ws_size,
                              hipStream_t stream)
{
    const float* x       = (const float*)d_in[0];
    const void*  src_trg = d_in[1];
    const float* W       = (const float*)d_in[2];
    const float* b       = (const float*)d_in[3];
    float*       out     = (float*)d_out;

    int n = in_sizes[0] / 128;
    long long m = in_sizes[1] / 2;
    int chunk = (n + SCB - 1) / SCB;
    long long padcap = m + 3LL * n + 4;   // worst-case padded edge count

    // workspace layout (~61 MB)
    float* h        = (float*)d_ws;                      // (n+1)*128 floats
    int*   cnt      = (int*)(h + (size_t)(n + 1) * 128); // n
    int*   row_ptr  = cnt + n;                           // n+1
    int*   cursor   = row_ptr + (n + 1);                 // n
    int*   edge_src = cursor + n;                        // padcap ints
    int*   idx64    = edge_src + padcap;                 // 1 flag
    int*   bsum     = idx64 + 1;                         // SCB
    int*   boff     = bsum + SCB;                        // SCB
    int*   total    = boff + SCB;                        // 1

    hipLaunchKernelGGL(gemm_norm_kernel, dim3((n + 31) / 32), dim3(256), 0, stream,
                       x, W, b, h, n);
    hipLaunchKernelGGL(prep_kernel, dim3(2048), dim3(256), 0, stream,
                       cnt, n, h, edge_src, padcap, (const int*)src_trg, idx64);
    hipLaunchKernelGGL(hist_kernel, dim3((int)((m + 255) / 256)), dim3(256), 0, stream,
                       src_trg, m, n, idx64, cnt);
    hipLaunchKernelGGL(scan_partial_kernel, dim3(SCB), dim3(256), 0, stream,
                       cnt, n, chunk, bsum);
    hipLaunchKernelGGL(scan_offsets_kernel, dim3(1), dim3(256), 0, stream,
                       bsum, SCB, boff, total);
    hipLaunchKernelGGL(scan_write_kernel, dim3(SCB), dim3(256), 0, stream,
                       cnt, n, chunk, boff, total, row_ptr, cursor);
    hipLaunchKernelGGL(scatter_kernel, dim3((int)((m + 255) / 256)), dim3(256), 0, stream,
                       src_trg, m, n, idx64, cursor, edge_src);
    hipLaunchKernelGGL(route_kernel, dim3((n + WPB - 1) / WPB), dim3(64 * WPB), 0, stream,
                       h, row_ptr, edge_src, out, n);
}